// Round 8
// baseline (278.334 us; speedup 1.0000x reference)
//
#include <hip/hip_runtime.h>
#include <math.h>

// NoisyTopKRouter: B=4, T=4096, C=2048, E=64, K=8; rows = 16384.
// (1) convert_w: split w into hi/lo bf16 packed in MFMA-fragment order.
// (2) router_fused: FULL-K fused GEMM + top-k epilogue. BM=64, 512-thr
//     (8 waves = 4 row-quarters x 2 col-halves), 32 stages of BK=64.
//     r3-validated schedule: both B k-chunk loads issued BEFORE the x
//     prefetch (counted vmcnt waits on B never drain x), counted-wait
//     barriers (no vmcnt(0) drain in loop), x prefetch depth 2, LDS
//     stage buffer double-buffered. Grid 256 = 1 block/CU, no tail.
//     Epilogue in-block: stage LDS re-used as score tile; per-wave
//     rank-by-counting top-8, sparse softmax, selective f64 near-tie
//     repair (validated numerics; full-K chain proven in round 1).
//     Eliminates the 67 MB part round-trip + third launch + its ramp.

#define CDIM   2048
#define EDIM   64
#define NOUT   128
#define TOPK   8
#define NROWS  16384
#define BM     64
#define BK     64                // floats per stage = 2 MFMA k-chunks
#define NIT    (CDIM / BK)       // 32
#define TAU    1e-3f
#define XPS    136               // stage row pitch (shorts): hi[64]|lo[64]|pad
#define SCP    132               // score tile row pitch (floats)

typedef __attribute__((ext_vector_type(8))) short bf16x8;
typedef __attribute__((ext_vector_type(4))) float f32x4;

__device__ __forceinline__ void split8(const float4 a, const float4 b,
                                       bf16x8& h8, bf16x8& l8) {
    const float vv[8] = {a.x, a.y, a.z, a.w, b.x, b.y, b.z, b.w};
    #pragma unroll
    for (int j = 0; j < 8; ++j) {
        const __bf16 h = (__bf16)vv[j];
        const __bf16 l = (__bf16)(vv[j] - (float)h);
        h8[j] = __builtin_bit_cast(short, h);
        l8[j] = __builtin_bit_cast(short, l);
    }
}

// barrier WITHOUT vmcnt(0) drain: LDS writes made visible, global loads
// stay in flight (compiler still emits counted vmcnt for register uses).
__device__ __forceinline__ void block_sync() {
    asm volatile("s_waitcnt lgkmcnt(0)" ::: "memory");
    __builtin_amdgcn_s_barrier();
}

// wave-private LDS visibility: DS pipe is in-order per wave, lanes are
// lockstep -> a counted-wait is enough, no s_barrier needed.
__device__ __forceinline__ void wave_lds_sync() {
    asm volatile("s_waitcnt lgkmcnt(0)" ::: "memory");
}

// ---- kernel 1: pack w into MFMA-fragment order, hi/lo bf16.
// slot s = (kc*8 + cg)*64 + lane holds w[col = cg*16 + (lane&15)]
//                                    [k = kc*32 + (lane>>4)*8 + j]
__global__ __launch_bounds__(256)
void convert_w(const float* __restrict__ wr, const float* __restrict__ wn,
               short* __restrict__ whi, short* __restrict__ wlo) {
    const int s    = (int)blockIdx.x * 256 + (int)threadIdx.x;  // 0..32767
    const int lane = s & 63;
    const int cg   = (s >> 6) & 7;
    const int kc   = s >> 9;
    const int col  = cg * 16 + (lane & 15);
    const int k0   = kc * 32 + (lane >> 4) * 8;
    const float* src = (col < EDIM ? wr + (size_t)col * CDIM
                                   : wn + (size_t)(col - EDIM) * CDIM) + k0;
    const float4 a = *(const float4*)src;
    const float4 b = *(const float4*)(src + 4);
    bf16x8 h8, l8; split8(a, b, h8, l8);
    *(bf16x8*)(whi + (size_t)s * 8) = h8;
    *(bf16x8*)(wlo + (size_t)s * 8) = l8;
}

// ---- kernel 2: fused full-K split-bf16 MFMA GEMM + top-k epilogue
__global__ __launch_bounds__(512)
void router_fused(const float* __restrict__ x,
                  const short* __restrict__ whi,
                  const short* __restrict__ wlo,
                  const float* __restrict__ w_route,
                  const float* __restrict__ w_noise,
                  const float* __restrict__ noise,
                  float* __restrict__ out_probs,
                  float* __restrict__ out_idx)
{
    __shared__ __align__(16) short xsh[2][BM][XPS];   // 34.8 KB
    __shared__ float vals[8][64];                     // 2 KB
    __shared__ float srt[8][64];                      // 2 KB

    const int tid  = (int)threadIdx.x;
    const int lane = tid & 63;
    const int wid  = tid >> 6;          // 0..7
    const int wr   = wid >> 1;          // row quarter (16 rows)
    const int wc   = wid & 1;           // col half (64 cols)
    const int l15  = lane & 15;
    const int q8   = (lane >> 4) * 8;
    const int q4   = (lane >> 4) * 4;
    const int row0 = (int)blockIdx.x * BM;

    // staging: thread = (row = tid>>3, oct = tid&7): 8 contiguous floats
    const int srow = tid >> 3;          // 0..63
    const int soct = tid & 7;           // 0..7
    const float* xsrc = x + (size_t)(row0 + srow) * CDIM + soct * 8;

    f32x4 acc[4];
    #pragma unroll
    for (int nc = 0; nc < 4; ++nc)
        acc[nc] = (f32x4){0.f, 0.f, 0.f, 0.f};

    // B frags: two k-chunk register sets, both issued at iteration top
    // (BEFORE x prefetch -> their in-order vmcnt waits never drain x).
    bf16x8 bh0[4], bl0[4], bh1[4], bl1[4];
    auto loadB0 = [&](int kc) {
        const int base = (kc * 8 + wc * 4) * 512 + lane * 8;
        #pragma unroll
        for (int nc = 0; nc < 4; ++nc) {
            bh0[nc] = *(const bf16x8*)(whi + base + nc * 512);
            bl0[nc] = *(const bf16x8*)(wlo + base + nc * 512);
        }
    };
    auto loadB1 = [&](int kc) {
        const int base = (kc * 8 + wc * 4) * 512 + lane * 8;
        #pragma unroll
        for (int nc = 0; nc < 4; ++nc) {
            bh1[nc] = *(const bf16x8*)(whi + base + nc * 512);
            bl1[nc] = *(const bf16x8*)(wlo + base + nc * 512);
        }
    };

    // x prefetch: 2 float4/thread per stage, depth 2
    float4 pf[2][2];
    auto issue = [&](int slot, int it) {
        pf[slot][0] = *(const float4*)(xsrc + it * BK);
        pf[slot][1] = *(const float4*)(xsrc + it * BK + 4);
    };
    auto stage = [&](int buf, int slot) {
        bf16x8 h8, l8; split8(pf[slot][0], pf[slot][1], h8, l8);
        *(bf16x8*)&xsh[buf][srow][soct * 8]      = h8;
        *(bf16x8*)&xsh[buf][srow][64 + soct * 8] = l8;
    };

    // prologue: x(0) staged, x(1) in regs (depth 2)
    issue(0, 0);
    stage(0, 0);
    issue(1, 1);
    block_sync();

    #pragma unroll 2
    for (int it = 0; it < NIT; ++it) {
        const int cur = it & 1;
        loadB0(2 * it);                       // B k-chunk 0 (L2-resident)
        loadB1(2 * it + 1);                   // B k-chunk 1
        if (it + 2 < NIT) issue(cur, it + 2); // x two stages ahead (HBM)

        const short* ar = &xsh[cur][wr * 16 + l15][0];
        {   // k-chunk 0
            const bf16x8 ah = *(const bf16x8*)(ar + q8);
            const bf16x8 al = *(const bf16x8*)(ar + 64 + q8);
            #pragma unroll
            for (int nc = 0; nc < 4; ++nc) {
                acc[nc] = __builtin_amdgcn_mfma_f32_16x16x32_bf16(ah, bh0[nc], acc[nc], 0, 0, 0);
                acc[nc] = __builtin_amdgcn_mfma_f32_16x16x32_bf16(al, bh0[nc], acc[nc], 0, 0, 0);
                acc[nc] = __builtin_amdgcn_mfma_f32_16x16x32_bf16(ah, bl0[nc], acc[nc], 0, 0, 0);
            }
        }
        {   // k-chunk 1
            const bf16x8 ah = *(const bf16x8*)(ar + 32 + q8);
            const bf16x8 al = *(const bf16x8*)(ar + 96 + q8);
            #pragma unroll
            for (int nc = 0; nc < 4; ++nc) {
                acc[nc] = __builtin_amdgcn_mfma_f32_16x16x32_bf16(ah, bh1[nc], acc[nc], 0, 0, 0);
                acc[nc] = __builtin_amdgcn_mfma_f32_16x16x32_bf16(al, bh1[nc], acc[nc], 0, 0, 0);
                acc[nc] = __builtin_amdgcn_mfma_f32_16x16x32_bf16(ah, bl1[nc], acc[nc], 0, 0, 0);
            }
        }
        if (it + 1 < NIT) {
            stage(cur ^ 1, cur ^ 1);   // x(it+1), issued 2 iters ago
            block_sync();
        }
    }

    // ---- epilogue: re-use xsh as the score tile [64][SCP]
    __syncthreads();   // full drain once: all waves done reading xsh
    float* scr = (float*)&xsh[0][0][0];   // 64*132*4 B = 33.8 KB <= 34.8 KB
    #pragma unroll
    for (int nc = 0; nc < 4; ++nc)
        #pragma unroll
        for (int g = 0; g < 4; ++g)
            scr[(wr * 16 + q4 + g) * SCP + wc * 64 + nc * 16 + l15] = acc[nc][g];
    __syncthreads();

    // wave wid handles rows wid*8 .. wid*8+7 (lane == expert index)
    #pragma unroll 1
    for (int r = 0; r < 8; ++r) {
        const int row  = wid * 8 + r;
        const int grow = row0 + row;

        const float route = scr[row * SCP + lane];
        const float nz    = scr[row * SCP + 64 + lane];
        const float nv    = noise[(size_t)grow * EDIM + lane];
        const float sp = fmaxf(nz, 0.f) + log1pf(expf(-fabsf(nz)));
        const float nl = route + nv * sp;

        vals[wid][lane] = nl;        // wave-private slice: no block barrier
        wave_lds_sync();

        // rank = #{j better}; "better" = (v_j > v_i) or tie with j < i
        int cnt = 0;
        #pragma unroll
        for (int jq = 0; jq < 16; ++jq) {
            const float4 v = *(const float4*)&vals[wid][jq * 4];
            const int j0 = jq * 4;
            cnt += (v.x > nl || (v.x == nl && (j0 + 0) < lane));
            cnt += (v.y > nl || (v.y == nl && (j0 + 1) < lane));
            cnt += (v.z > nl || (v.z == nl && (j0 + 2) < lane));
            cnt += (v.w > nl || (v.w == nl && (j0 + 3) < lane));
        }
        srt[wid][cnt] = nl;   // ranks are a permutation of 0..63
        wave_lds_sync();

        const float m = srt[wid][0];
        // gap scan over the 8 ranking-relevant boundaries (wave-uniform)
        bool amb = false, flagme = false;
        float prev = m;
        #pragma unroll
        for (int t = 1; t <= TOPK; ++t) {
            const float vt = srt[wid][t];
            if (prev - vt < TAU) {
                amb = true;
                const float vb = 0.5f * (prev + vt);
                flagme = flagme || (fabsf(nl - vb) <= TAU);
            }
            prev = vt;
        }

        if (cnt < TOPK) out_idx[(size_t)grow * TOPK + cnt] = (float)lane;
        float ev = (cnt < TOPK) ? expf(nl - m) : 0.f;
        float s  = ev;
        #pragma unroll
        for (int off = 32; off >= 1; off >>= 1) s += __shfl_xor(s, off, 64);
        out_probs[(size_t)grow * EDIM + lane] = ev / s;

        if (amb) {
            // selective f64 repair: exact dots only for flagged experts
            unsigned long long mask = __ballot(flagme);
            double nld = (double)nl;
            const float* xr = x + (size_t)grow * CDIM;
            while (mask) {
                const int e = (int)__ffsll(mask) - 1;
                mask &= (mask - 1);
                double ar2 = 0.0, an = 0.0;
                const float* wrp = w_route + (size_t)e * CDIM;
                const float* wnp = w_noise + (size_t)e * CDIM;
                #pragma unroll
                for (int j = 0; j < 8; ++j) {
                    const int k = (j * 64 + lane) * 4;   // coalesced
                    const float4 xv = *(const float4*)(xr + k);
                    const float4 rv = *(const float4*)(wrp + k);
                    const float4 nq = *(const float4*)(wnp + k);
                    ar2 = fma((double)xv.x, (double)rv.x, ar2);
                    ar2 = fma((double)xv.y, (double)rv.y, ar2);
                    ar2 = fma((double)xv.z, (double)rv.z, ar2);
                    ar2 = fma((double)xv.w, (double)rv.w, ar2);
                    an  = fma((double)xv.x, (double)nq.x, an);
                    an  = fma((double)xv.y, (double)nq.y, an);
                    an  = fma((double)xv.z, (double)nq.z, an);
                    an  = fma((double)xv.w, (double)nq.w, an);
                }
                #pragma unroll
                for (int off = 32; off >= 1; off >>= 1) {
                    ar2 += __shfl_xor(ar2, off, 64);
                    an  += __shfl_xor(an, off, 64);
                }
                const double spd = fmax(an, 0.0) + log1p(exp(-fabs(an)));
                const double nve = (double)__shfl(nv, e, 64);
                const double v   = ar2 + nve * spd;
                if (lane == e) nld = v;
            }
            double workd = nld;
            int    rank2 = -1;
            double m2 = 0.0;
            #pragma unroll
            for (int t = 0; t < TOPK; ++t) {
                double bv = workd;
                int    bi = lane;
                #pragma unroll
                for (int off = 32; off >= 1; off >>= 1) {
                    const double ov = __shfl_xor(bv, off, 64);
                    const int    oi = __shfl_xor(bi, off, 64);
                    if (ov > bv || (ov == bv && oi < bi)) { bv = ov; bi = oi; }
                }
                if (t == 0) m2 = bv;
                if (lane == bi) {
                    rank2 = t;
                    workd = -INFINITY;
                    out_idx[(size_t)grow * TOPK + t] = (float)lane;
                }
            }
            float ev2 = (rank2 >= 0) ? expf((float)(nld - m2)) : 0.f;
            float s2  = ev2;
            #pragma unroll
            for (int off = 32; off >= 1; off >>= 1) s2 += __shfl_xor(s2, off, 64);
            out_probs[(size_t)grow * EDIM + lane] = ev2 / s2;
        }
    }
}

extern "C" void kernel_launch(void* const* d_in, const int* in_sizes, int n_in,
                              void* d_out, int out_size, void* d_ws, size_t ws_size,
                              hipStream_t stream)
{
    const float* x       = (const float*)d_in[0];
    const float* w_route = (const float*)d_in[1];
    const float* w_noise = (const float*)d_in[2];
    const float* noise   = (const float*)d_in[3];

    const int n_rows = in_sizes[0] / CDIM;                 // 16384
    float* out_probs = (float*)d_out;                      // (B,T,E) fp32
    float* out_idx   = out_probs + (size_t)n_rows * EDIM;  // (B,T,K) as fp32

    short* whi = (short*)d_ws;                             // 512 KB packed hi
    short* wlo = whi + (size_t)NOUT * CDIM;                // 512 KB packed lo

    hipLaunchKernelGGL(convert_w, dim3(NOUT * CDIM / (256 * 8)), dim3(256), 0, stream,
                       w_route, w_noise, whi, wlo);
    hipLaunchKernelGGL(router_fused, dim3(n_rows / BM), dim3(512), 0, stream,
                       x, whi, wlo, w_route, w_noise, noise, out_probs, out_idx);
}

// Round 11
// 257.476 us; speedup vs baseline: 1.0810x; 1.0810x over previous
//
#include <hip/hip_runtime.h>
#include <math.h>

// NoisyTopKRouter: B=4, T=4096, C=2048, E=64, K=8; rows = 16384.
// (1) convert_w: split w into hi/lo bf16 packed in MFMA-fragment order.
// (2) router_gemm: split-bf16 MFMA, BM=32, BK=128 (one 512B burst per
//     row per stage), KSPLIT=4, 128-thr blocks, 8 blocks/CU, grid 2048
//     fully resident. Counted-wait barriers, depth-1 stage prefetch.
//     (Best measured structure, r7 — unchanged.)
// (3) router_epilogue: 1024 blocks x 16 rows (4 rows/wave), depth-2
//     row software pipeline (next row's 9 loads issued before current
//     row's ranking) with compile-time pipeline slots (full unroll).
//     Rank-by-counting top-8, wave-private LDS sync, sparse softmax,
//     selective f64 near-tie repair (validated numerics, unchanged).

#define CDIM   2048
#define EDIM   64
#define NOUT   128
#define POUT   512               // part row pitch: 4 quarters x 128
#define TOPK   8
#define NROWS  16384
#define BM     32
#define BK     128               // floats per stage = 4 MFMA k-chunks
#define KSPLIT 4
#define KQ     (CDIM / KSPLIT)   // 512
#define NIT    (KQ / BK)         // 4
#define TAU    1e-3f
#define XPS    72                // slab row pitch (shorts): hi[32]|lo[32]|pad
#define EROWS  16                // epilogue rows per block (4 per wave)

typedef __attribute__((ext_vector_type(8))) short bf16x8;
typedef __attribute__((ext_vector_type(4))) float f32x4;

__device__ __forceinline__ void split8(const float4 a, const float4 b,
                                       bf16x8& h8, bf16x8& l8) {
    const float vv[8] = {a.x, a.y, a.z, a.w, b.x, b.y, b.z, b.w};
    #pragma unroll
    for (int j = 0; j < 8; ++j) {
        const __bf16 h = (__bf16)vv[j];
        const __bf16 l = (__bf16)(vv[j] - (float)h);
        h8[j] = __builtin_bit_cast(short, h);
        l8[j] = __builtin_bit_cast(short, l);
    }
}

// barrier WITHOUT vmcnt(0) drain: LDS writes made visible, global loads
// stay in flight (compiler still emits counted vmcnt for register uses).
__device__ __forceinline__ void block_sync() {
    asm volatile("s_waitcnt lgkmcnt(0)" ::: "memory");
    __builtin_amdgcn_s_barrier();
}

// wave-private LDS visibility: DS pipe is in-order per wave, lanes are
// lockstep -> a counted-wait is enough, no s_barrier needed.
__device__ __forceinline__ void wave_lds_sync() {
    asm volatile("s_waitcnt lgkmcnt(0)" ::: "memory");
}

// ---- kernel 1: pack w into MFMA-fragment order, hi/lo bf16.
// slot s = (kc*8 + cg)*64 + lane holds w[col = cg*16 + (lane&15)]
//                                    [k = kc*32 + (lane>>4)*8 + j]
__global__ __launch_bounds__(256)
void convert_w(const float* __restrict__ wr, const float* __restrict__ wn,
               short* __restrict__ whi, short* __restrict__ wlo) {
    const int s    = (int)blockIdx.x * 256 + (int)threadIdx.x;  // 0..32767
    const int lane = s & 63;
    const int cg   = (s >> 6) & 7;
    const int kc   = s >> 9;
    const int col  = cg * 16 + (lane & 15);
    const int k0   = kc * 32 + (lane >> 4) * 8;
    const float* src = (col < EDIM ? wr + (size_t)col * CDIM
                                   : wn + (size_t)(col - EDIM) * CDIM) + k0;
    const float4 a = *(const float4*)src;
    const float4 b = *(const float4*)(src + 4);
    bf16x8 h8, l8; split8(a, b, h8, l8);
    *(bf16x8*)(whi + (size_t)s * 8) = h8;
    *(bf16x8*)(wlo + (size_t)s * 8) = l8;
}

// ---- kernel 2: split-bf16 MFMA GEMM, BM=32/BK=128, K-split x4
__global__ __launch_bounds__(128, 4)
void router_gemm(const float* __restrict__ x,
                 const short* __restrict__ whi,
                 const short* __restrict__ wlo,
                 float* __restrict__ part)
{
    __shared__ __align__(16) short xsh[4][BM][XPS];   // 18.4 KB (4 kc slabs)

    const int tid  = (int)threadIdx.x;
    const int lane = tid & 63;
    const int wc   = tid >> 6;          // 0..1: col half (64 cols)
    const int l15  = lane & 15;
    const int q8   = (lane >> 4) * 8;
    const int q4   = (lane >> 4) * 4;
    const int bi   = (int)blockIdx.x;
    const int qk   = bi & (KSPLIT - 1);
    const int row0 = (bi >> 2) * BM;

    // staging: thread -> (row = tid>>2, slab j = tid&3), 32 contiguous
    // floats = 128B; 4 threads/row issued together = 512B/row burst.
    const int srow = tid >> 2;          // 0..31
    const int sj   = tid & 3;           // kc-slab within stage
    const float* xsrc = x + (size_t)(row0 + srow) * CDIM + qk * KQ + sj * 32;

    f32x4 acc[2][4];
    #pragma unroll
    for (int mr = 0; mr < 2; ++mr)
        #pragma unroll
        for (int nc = 0; nc < 4; ++nc)
            acc[mr][nc] = (f32x4){0.f, 0.f, 0.f, 0.f};

    // depth-1 register prefetch: one stage (32 floats) in flight
    float4 pf[8];
    auto issue = [&](int it) {
        #pragma unroll
        for (int v = 0; v < 8; ++v)
            pf[v] = *(const float4*)(xsrc + it * BK + v * 4);
    };
    auto write_pf = [&]() {
        #pragma unroll
        for (int h = 0; h < 4; ++h) {
            bf16x8 h8, l8; split8(pf[2 * h], pf[2 * h + 1], h8, l8);
            *(bf16x8*)&xsh[sj][srow][h * 8]      = h8;
            *(bf16x8*)&xsh[sj][srow][32 + h * 8] = l8;
        }
    };

    // B frags direct from global (packed, coalesced lane*16), per kc
    bf16x8 bh[4], bl[4];
    auto loadB = [&](int kcq) {   // kcq = k-chunk within this quarter, 0..15
        const int base = ((qk * 16 + kcq) * 8 + wc * 4) * 512 + lane * 8;
        #pragma unroll
        for (int nc = 0; nc < 4; ++nc) {
            bh[nc] = *(const bf16x8*)(whi + base + nc * 512);
            bl[nc] = *(const bf16x8*)(wlo + base + nc * 512);
        }
    };

    // prologue: stage(0) -> LDS; stage(1) -> regs
    issue(0);
    write_pf();
    issue(1);
    block_sync();

    #pragma unroll
    for (int it = 0; it < NIT; ++it) {
        // compute: 4 kc slabs from LDS (written at previous stage phase)
        #pragma unroll
        for (int j = 0; j < 4; ++j) {
            loadB(it * 4 + j);
            bf16x8 ah[2], al[2];
            ah[0] = *(const bf16x8*)(&xsh[j][l15][q8]);
            al[0] = *(const bf16x8*)(&xsh[j][l15][32 + q8]);
            ah[1] = *(const bf16x8*)(&xsh[j][16 + l15][q8]);
            al[1] = *(const bf16x8*)(&xsh[j][16 + l15][32 + q8]);
            #pragma unroll
            for (int mr = 0; mr < 2; ++mr)
                #pragma unroll
                for (int nc = 0; nc < 4; ++nc) {
                    acc[mr][nc] = __builtin_amdgcn_mfma_f32_16x16x32_bf16(ah[mr], bh[nc], acc[mr][nc], 0, 0, 0);
                    acc[mr][nc] = __builtin_amdgcn_mfma_f32_16x16x32_bf16(al[mr], bh[nc], acc[mr][nc], 0, 0, 0);
                    acc[mr][nc] = __builtin_amdgcn_mfma_f32_16x16x32_bf16(ah[mr], bl[nc], acc[mr][nc], 0, 0, 0);
                }
        }
        if (it + 1 < NIT) {
            block_sync();            // all waves done reading xsh
            write_pf();              // stage x(it+1) (vmcnt waits on pf)
            if (it + 2 < NIT) issue(it + 2);
            block_sync();            // writes visible
        }
    }

    // partial store, row-interleaved part layout [row][qk*128 + col]
    // (C/D layout: row = quad*4+reg, col = lane&15)
    #pragma unroll
    for (int mr = 0; mr < 2; ++mr)
        #pragma unroll
        for (int nc = 0; nc < 4; ++nc)
            #pragma unroll
            for (int g = 0; g < 4; ++g)
                part[(size_t)(row0 + mr * 16 + q4 + g) * POUT
                     + qk * NOUT + wc * 64 + nc * 16 + l15] = acc[mr][nc][g];
}

// ---- kernel 3: rank-by-counting epilogue; wave = 4 rows, depth-2
//      row software pipeline (compile-time slots via full unroll)
__global__ __launch_bounds__(256, 4)
void router_epilogue(const float* __restrict__ x,
                     const float* __restrict__ w_route,
                     const float* __restrict__ w_noise,
                     const float* __restrict__ noise,
                     const float* __restrict__ part,
                     float* __restrict__ out_probs,
                     float* __restrict__ out_idx)
{
    __shared__ float vals[4][64];
    __shared__ float srt[4][64];

    const int tid   = (int)threadIdx.x;
    const int lane  = tid & 63;   // lane == expert index
    const int wid   = tid >> 6;
    const int rbase = (int)blockIdx.x * EROWS + wid * 4;

    float pr[2][4], pn[2][4], pv[2];
    auto issue_row = [&](int slot, int r) {
        const int grow  = rbase + r;
        const size_t ro = (size_t)grow * POUT;
        #pragma unroll
        for (int q = 0; q < 4; ++q) {
            pr[slot][q] = part[ro + q * NOUT + lane];
            pn[slot][q] = part[ro + q * NOUT + 64 + lane];
        }
        pv[slot] = noise[(size_t)grow * EDIM + lane];
    };
    issue_row(0, 0);

    #pragma unroll   // FULL unroll: slot indices become compile-time
    for (int r = 0; r < 4; ++r) {
        const int slot = r & 1;
        if (r + 1 < 4) issue_row(slot ^ 1, r + 1);
        const int grow = rbase + r;

        const float route = (pr[slot][0] + pr[slot][1]) + (pr[slot][2] + pr[slot][3]);
        const float nz    = (pn[slot][0] + pn[slot][1]) + (pn[slot][2] + pn[slot][3]);
        const float nv    = pv[slot];
        const float sp = fmaxf(nz, 0.f) + log1pf(expf(-fabsf(nz)));
        const float nl = route + nv * sp;

        vals[wid][lane] = nl;        // wave-private slice: no block barrier
        wave_lds_sync();

        // rank = #{j better}; "better" = (v_j > v_i) or tie with j < i
        int cnt = 0;
        #pragma unroll
        for (int jq = 0; jq < 16; ++jq) {
            const float4 v = *(const float4*)&vals[wid][jq * 4];
            const int j0 = jq * 4;
            cnt += (v.x > nl || (v.x == nl && (j0 + 0) < lane));
            cnt += (v.y > nl || (v.y == nl && (j0 + 1) < lane));
            cnt += (v.z > nl || (v.z == nl && (j0 + 2) < lane));
            cnt += (v.w > nl || (v.w == nl && (j0 + 3) < lane));
        }
        srt[wid][cnt] = nl;   // ranks are a permutation of 0..63
        wave_lds_sync();

        const float m = srt[wid][0];
        // gap scan over the 8 ranking-relevant boundaries (wave-uniform)
        bool amb = false, flagme = false;
        float prev = m;
        #pragma unroll
        for (int t = 1; t <= TOPK; ++t) {
            const float vt = srt[wid][t];
            if (prev - vt < TAU) {
                amb = true;
                const float vb = 0.5f * (prev + vt);
                flagme = flagme || (fabsf(nl - vb) <= TAU);
            }
            prev = vt;
        }

        if (cnt < TOPK) out_idx[(size_t)grow * TOPK + cnt] = (float)lane;
        float ev = (cnt < TOPK) ? expf(nl - m) : 0.f;
        float s  = ev;
        #pragma unroll
        for (int off = 32; off >= 1; off >>= 1) s += __shfl_xor(s, off, 64);
        out_probs[(size_t)grow * EDIM + lane] = ev / s;

        if (amb) {
            // selective f64 repair: exact dots only for flagged experts
            unsigned long long mask = __ballot(flagme);
            double nld = (double)nl;
            const float* xr = x + (size_t)grow * CDIM;
            while (mask) {
                const int e = (int)__ffsll(mask) - 1;
                mask &= (mask - 1);
                double ar = 0.0, an = 0.0;
                const float* wrp = w_route + (size_t)e * CDIM;
                const float* wnp = w_noise + (size_t)e * CDIM;
                #pragma unroll
                for (int j = 0; j < 8; ++j) {
                    const int k = (j * 64 + lane) * 4;   // coalesced
                    const float4 xv = *(const float4*)(xr + k);
                    const float4 rv = *(const float4*)(wrp + k);
                    const float4 nq = *(const float4*)(wnp + k);
                    ar = fma((double)xv.x, (double)rv.x, ar);
                    ar = fma((double)xv.y, (double)rv.y, ar);
                    ar = fma((double)xv.z, (double)rv.z, ar);
                    ar = fma((double)xv.w, (double)rv.w, ar);
                    an = fma((double)xv.x, (double)nq.x, an);
                    an = fma((double)xv.y, (double)nq.y, an);
                    an = fma((double)xv.z, (double)nq.z, an);
                    an = fma((double)xv.w, (double)nq.w, an);
                }
                #pragma unroll
                for (int off = 32; off >= 1; off >>= 1) {
                    ar += __shfl_xor(ar, off, 64);
                    an += __shfl_xor(an, off, 64);
                }
                const double spd = fmax(an, 0.0) + log1p(exp(-fabs(an)));
                const double nve = (double)__shfl(nv, e, 64);
                const double v   = ar + nve * spd;
                if (lane == e) nld = v;
            }
            double workd = nld;
            int    rank2 = -1;
            double m2 = 0.0;
            #pragma unroll
            for (int t = 0; t < TOPK; ++t) {
                double bv = workd;
                int    bi = lane;
                #pragma unroll
                for (int off = 32; off >= 1; off >>= 1) {
                    const double ov = __shfl_xor(bv, off, 64);
                    const int    oi = __shfl_xor(bi, off, 64);
                    if (ov > bv || (ov == bv && oi < bi)) { bv = ov; bi = oi; }
                }
                if (t == 0) m2 = bv;
                if (lane == bi) {
                    rank2 = t;
                    workd = -INFINITY;
                    out_idx[(size_t)grow * TOPK + t] = (float)lane;
                }
            }
            float ev2 = (rank2 >= 0) ? expf((float)(nld - m2)) : 0.f;
            float s2  = ev2;
            #pragma unroll
            for (int off = 32; off >= 1; off >>= 1) s2 += __shfl_xor(s2, off, 64);
            out_probs[(size_t)grow * EDIM + lane] = ev2 / s2;
        }
    }
}

extern "C" void kernel_launch(void* const* d_in, const int* in_sizes, int n_in,
                              void* d_out, int out_size, void* d_ws, size_t ws_size,
                              hipStream_t stream)
{
    const float* x       = (const float*)d_in[0];
    const float* w_route = (const float*)d_in[1];
    const float* w_noise = (const float*)d_in[2];
    const float* noise   = (const float*)d_in[3];

    const int n_rows = in_sizes[0] / CDIM;                 // 16384
    float* out_probs = (float*)d_out;                      // (B,T,E) fp32
    float* out_idx   = out_probs + (size_t)n_rows * EDIM;  // (B,T,K) as fp32

    short* whi  = (short*)d_ws;                            // 512 KB packed hi
    short* wlo  = whi + (size_t)NOUT * CDIM;               // 512 KB packed lo
    float* part = (float*)((char*)d_ws + 2u * 1024u * 1024u); // 16384 x 512 f32

    hipLaunchKernelGGL(convert_w, dim3(NOUT * CDIM / (256 * 8)), dim3(256), 0, stream,
                       w_route, w_noise, whi, wlo);
    hipLaunchKernelGGL(router_gemm, dim3((n_rows / BM) * KSPLIT), dim3(128), 0, stream,
                       x, whi, wlo, part);
    hipLaunchKernelGGL(router_epilogue, dim3(n_rows / EROWS), dim3(256), 0, stream,
                       x, w_route, w_noise, noise, part, out_probs, out_idx);
}